// Round 8
// baseline (611.951 us; speedup 1.0000x reference)
//
#include <hip/hip_runtime.h>
#include <hip/hip_bf16.h>

#define C_NUM 100000
#define D_EMB 512
#define N_BATCH 512
#define SCALE_F 30.0f
#define MARGIN_F 0.4f
#define H_F 0.333f
#define NT2 782              // ceil(100000/128) class tiles
#define KSTEPS 16            // 512 / 32

typedef __attribute__((ext_vector_type(8))) short bf16x8;
typedef __attribute__((ext_vector_type(4))) short bf16x4;
typedef __attribute__((ext_vector_type(4))) float f32x4;

static __device__ __forceinline__ short f2bf(float f) {
  __hip_bfloat16 h = __float2bfloat16(f);
  union { __hip_bfloat16 b; short s; } u;
  u.b = h;
  return u.s;
}

static __device__ __forceinline__ float sq4(f32x4 v) {
  return v[0]*v[0] + v[1]*v[1] + v[2]*v[2] + v[3]*v[3];
}

// async global -> LDS, 16 B per lane (dest = wave-uniform base + lane*16)
static __device__ __forceinline__ void gload16(const void* g, void* l) {
  __builtin_amdgcn_global_load_lds(
      (const __attribute__((address_space(1))) void*)g,
      (__attribute__((address_space(3))) void*)l, 16, 0, 0);
}

// ---------------------------------------------------------------------------
// Kernel 1: per-row L2 norm of embeddings; unit-normalized rows as bf16.
// ---------------------------------------------------------------------------
__global__ __launch_bounds__(64) void k_rownorm(const float* __restrict__ emb,
                                                short* __restrict__ Aunit,
                                                float* __restrict__ norms) {
  const int i = blockIdx.x;
  const int l = threadIdx.x;
  const f32x4* row = reinterpret_cast<const f32x4*>(emb + (size_t)i * D_EMB);
  f32x4 v0 = row[l];
  f32x4 v1 = row[l + 64];
  float ss = sq4(v0) + sq4(v1);
#pragma unroll
  for (int m = 1; m < 64; m <<= 1) ss += __shfl_xor(ss, m);
  float nrm = sqrtf(ss);
  float inv = 1.0f / nrm;
  bf16x4 o0, o1;
#pragma unroll
  for (int q = 0; q < 4; ++q) { o0[q] = f2bf(v0[q] * inv); o1[q] = f2bf(v1[q] * inv); }
  bf16x4* dst = reinterpret_cast<bf16x4*>(Aunit + (size_t)i * D_EMB);
  dst[l] = o0;
  dst[l + 64] = o1;
  if (l == 0) norms[i] = nrm;
}

// ---------------------------------------------------------------------------
// Kernel 2: batch mean / unbiased std -> adaptive margin per row.
// ---------------------------------------------------------------------------
__global__ __launch_bounds__(512) void k_stats(const float* __restrict__ norms,
                                               float* __restrict__ marg) {
  __shared__ float red[8];
  const int t = threadIdx.x;
  const int lane = t & 63, wid = t >> 6;
  float x = norms[t];
  float s = x;
#pragma unroll
  for (int m = 1; m < 64; m <<= 1) s += __shfl_xor(s, m);
  if (lane == 0) red[wid] = s;
  __syncthreads();
  float tot = 0.f;
#pragma unroll
  for (int q = 0; q < 8; ++q) tot += red[q];
  const float mean = tot / 512.f;
  __syncthreads();
  float d = x - mean;
  float s2 = d * d;
#pragma unroll
  for (int m = 1; m < 64; m <<= 1) s2 += __shfl_xor(s2, m);
  if (lane == 0) red[wid] = s2;
  __syncthreads();
  float tot2 = 0.f;
#pragma unroll
  for (int q = 0; q < 8; ++q) tot2 += red[q];
  const float stdv = sqrtf(tot2 / 511.f);   // ddof=1
  float msc = (x - mean) / (stdv + H_F);
  msc = fminf(1.f, fmaxf(-1.f, msc));
  marg[t] = MARGIN_F * (1.f + msc);
}

// ---------------------------------------------------------------------------
// Kernel 3: m97-structure GEMM block, fused AdaFace epilogue.
// BM=BN=128, BK=32, 4 waves (2x2 of 64x64), 16x16x32 bf16 MFMA.
// A (bf16, 8 KB/step) and B (f32, 16 KB/step) staged via global_load_lds
// width 16 into double-buffered LDS. Bank-conflict XOR swizzle applied by
// pre-swizzling the per-lane GLOBAL source address; reads apply the same
// involution to the full byte offset (key bits 7+ disjoint from modified
// bits 4-6). Per-class ssq accumulated from staged f32 B-frags in regs.
// Grid 98*32=3136: bid -> (g=bid>>5, rt=(bid>>3)&3, ct=g*8+(bid&7));
// bid%8 == ct%8 -> the 4 rt-sharers of a class tile land on one XCD.
// ---------------------------------------------------------------------------
__global__ __launch_bounds__(256, 3) void k_main(const short* __restrict__ Aunit,
                                                 const float* __restrict__ weight,
                                                 const int* __restrict__ labels,
                                                 const float* __restrict__ marg,
                                                 float* __restrict__ partial,
                                                 float* __restrict__ tlogit) {
  __shared__ char As[2][8192];      // A tile: [128 rows][64 B] bf16
  __shared__ char Bsm[2][16384];    // B tile: [128 classes][128 B] f32
  __shared__ float rowsum[128][2];

  const int bid = blockIdx.x;
  const int grp = bid >> 5, within = bid & 31;
  const int rt = within >> 3;
  const int ct = grp * 8 + (within & 7);
  if (ct >= NT2) return;

  const int tid = threadIdx.x;
  const int wid = tid >> 6, lane = tid & 63;
  const int llo = lane & 15, lhi = lane >> 4;
  const int wr = wid >> 1, wc = wid & 1;

  // ---- per-lane global stage sources (pre-swizzled) ----
  const char* gA[2];
  const char* gB[4];
  {
    const char* Ab = (const char*)Aunit;
#pragma unroll
    for (int i = 0; i < 2; ++i) {
      unsigned p = wid * 2048 + i * 1024 + lane * 16;   // physical LDS offset
      unsigned o = p ^ (((p >> 7) & 3u) << 4);          // logical (involution)
      unsigned row = o >> 6, kb = o & 63;
      gA[i] = Ab + (size_t)(rt * 128 + row) * 1024 + kb;
    }
    const char* Wb = (const char*)weight;
#pragma unroll
    for (int i = 0; i < 4; ++i) {
      unsigned p = wid * 4096 + i * 1024 + lane * 16;
      unsigned o = p ^ (((p >> 7) & 7u) << 4);
      unsigned cls = o >> 7, kb = o & 127;
      int gcl = ct * 128 + (int)cls;
      if (gcl > C_NUM - 1) gcl = C_NUM - 1;             // clamp; masked in epilogue
      gB[i] = Wb + (size_t)gcl * 2048 + kb;
    }
  }

  // ---- lane-static physical ds_read offsets (same involutions) ----
  int pa[4], pb0[4], pb1[4];
#pragma unroll
  for (int mi = 0; mi < 4; ++mi) {
    int o = (wr * 64 + mi * 16 + llo) * 64 + lhi * 16;
    pa[mi] = o ^ (((o >> 7) & 3) << 4);
  }
#pragma unroll
  for (int ni = 0; ni < 4; ++ni) {
    int o = (wc * 64 + ni * 16 + llo) * 128 + lhi * 32;
    pb0[ni] = o ^ (((o >> 7) & 7) << 4);
    int o1 = o + 16;
    pb1[ni] = o1 ^ (((o1 >> 7) & 7) << 4);
  }

  f32x4 acc[4][4];
#pragma unroll
  for (int mi = 0; mi < 4; ++mi)
#pragma unroll
    for (int ni = 0; ni < 4; ++ni)
#pragma unroll
      for (int q = 0; q < 4; ++q) acc[mi][ni][q] = 0.f;
  float ssq[4] = {0.f, 0.f, 0.f, 0.f};

  // ---- prologue: stage K-step 0 into buffer 0 ----
#pragma unroll
  for (int i = 0; i < 2; ++i) gload16(gA[i], &As[0][wid * 2048 + i * 1024]);
#pragma unroll
  for (int i = 0; i < 4; ++i) gload16(gB[i], &Bsm[0][wid * 4096 + i * 1024]);
#pragma unroll
  for (int i = 0; i < 2; ++i) gA[i] += 64;    // advance to k0=32
#pragma unroll
  for (int i = 0; i < 4; ++i) gB[i] += 128;
  __syncthreads();

  int cur = 0;
  for (int t = 0; t < KSTEPS; ++t) {
    // stage next K-step into the other buffer (issue BEFORE compute)
    if (t < KSTEPS - 1) {
#pragma unroll
      for (int i = 0; i < 2; ++i) gload16(gA[i], &As[cur ^ 1][wid * 2048 + i * 1024]);
#pragma unroll
      for (int i = 0; i < 4; ++i) gload16(gB[i], &Bsm[cur ^ 1][wid * 4096 + i * 1024]);
#pragma unroll
      for (int i = 0; i < 2; ++i) gA[i] += 64;
#pragma unroll
      for (int i = 0; i < 4; ++i) gB[i] += 128;
    }

    // compute current buffer
    const char* Ab = As[cur];
    const char* Bb = Bsm[cur];
    bf16x8 a[4];
#pragma unroll
    for (int mi = 0; mi < 4; ++mi)
      a[mi] = *reinterpret_cast<const bf16x8*>(Ab + pa[mi]);
#pragma unroll
    for (int ni = 0; ni < 4; ++ni) {
      f32x4 bl = *reinterpret_cast<const f32x4*>(Bb + pb0[ni]);
      f32x4 bh = *reinterpret_cast<const f32x4*>(Bb + pb1[ni]);
      ssq[ni] += sq4(bl) + sq4(bh);
      bf16x8 b;
#pragma unroll
      for (int e = 0; e < 4; ++e) { b[e] = f2bf(bl[e]); b[e + 4] = f2bf(bh[e]); }
#pragma unroll
      for (int mi = 0; mi < 4; ++mi)
        acc[mi][ni] = __builtin_amdgcn_mfma_f32_16x16x32_bf16(a[mi], b, acc[mi][ni], 0, 0, 0);
    }

    __syncthreads();   // drains vmcnt -> next buffer ready; readers done with cur
    cur ^= 1;
  }

  // ---- per-class 1/||w||: merge k-slices across lhi groups ----
#pragma unroll
  for (int ni = 0; ni < 4; ++ni) {
    float s = ssq[ni];
    s += __shfl_xor(s, 16);
    s += __shfl_xor(s, 32);
    ssq[ni] = (s > 0.f) ? rsqrtf(s) : 0.f;
  }

  // ---- epilogue: margin at label, per-row exp sums ----
  const int rowbase = rt * 128 + wr * 64;
  const int colbase = ct * 128 + wc * 64;
#pragma unroll
  for (int mi = 0; mi < 4; ++mi) {
#pragma unroll
    for (int reg = 0; reg < 4; ++reg) {
      const int R = rowbase + mi * 16 + lhi * 4 + reg;   // C/D: row=(lane>>4)*4+reg
      const int lab = labels[R];
      float v = 0.f;
#pragma unroll
      for (int ni = 0; ni < 4; ++ni) {
        const int gcc = colbase + ni * 16 + llo;         // C/D: col=lane&15
        const float cosv = acc[mi][ni][reg] * ssq[ni];
        float lg = SCALE_F * cosv;
        if (lab == gcc) {
          float ctv = fminf(1.f, fmaxf(-1.f, cosv));
          float lt = SCALE_F * cosf(acosf(ctv) + marg[R]);
          lg = lt;
          tlogit[R] = lt;
        }
        v += (gcc < C_NUM) ? __expf(lg) : 0.f;
      }
      v += __shfl_xor(v, 1);
      v += __shfl_xor(v, 2);
      v += __shfl_xor(v, 4);
      v += __shfl_xor(v, 8);
      if (llo == 0) rowsum[wr * 64 + mi * 16 + lhi * 4 + reg][wc] = v;
    }
  }
  __syncthreads();
  if (tid < 128)
    partial[(size_t)ct * N_BATCH + rt * 128 + tid] = rowsum[tid][0] + rowsum[tid][1];
}

// ---------------------------------------------------------------------------
// Kernel 4: per-row reduce over class tiles: term[r] = log(sum) - tlogit[r]
// ---------------------------------------------------------------------------
__global__ __launch_bounds__(64) void k_reduce(const float* __restrict__ partial,
                                               const float* __restrict__ tlogit,
                                               float* __restrict__ term) {
  const int r = blockIdx.x;
  const int l = threadIdx.x;
  float s = 0.f;
  for (int b = l; b < NT2; b += 64)
    s += partial[(size_t)b * N_BATCH + r];
#pragma unroll
  for (int m = 1; m < 64; m <<= 1) s += __shfl_xor(s, m);
  if (l == 0) term[r] = logf(s) - tlogit[r];
}

// ---------------------------------------------------------------------------
// Kernel 5: loss = mean(term)
// ---------------------------------------------------------------------------
__global__ __launch_bounds__(512) void k_final(const float* __restrict__ term,
                                               float* __restrict__ out) {
  __shared__ float red[8];
  const int t = threadIdx.x;
  const int lane = t & 63, wid = t >> 6;
  float v = term[t];
#pragma unroll
  for (int m = 1; m < 64; m <<= 1) v += __shfl_xor(v, m);
  if (lane == 0) red[wid] = v;
  __syncthreads();
  if (t == 0) {
    float tot = 0.f;
#pragma unroll
    for (int q = 0; q < 8; ++q) tot += red[q];
    out[0] = tot / 512.f;
  }
}

extern "C" void kernel_launch(void* const* d_in, const int* in_sizes, int n_in,
                              void* d_out, int out_size, void* d_ws, size_t ws_size,
                              hipStream_t stream) {
  const float* emb    = (const float*)d_in[0];
  const int*   labels = (const int*)d_in[1];
  const float* weight = (const float*)d_in[2];
  float* out = (float*)d_out;

  char* ws = (char*)d_ws;
  short* Aunit   = (short*)ws;                        // 512*512*2 = 524288 B
  float* norms   = (float*)(ws + 524288);             // 2 KiB
  float* marg    = (float*)(ws + 524288 + 2048);      // 2 KiB
  float* tlog    = (float*)(ws + 524288 + 4096);      // 2 KiB
  float* term    = (float*)(ws + 524288 + 6144);      // 2 KiB
  float* partial = (float*)(ws + 524288 + 8192);      // 782*512*4 = 1601536 B

  k_rownorm<<<N_BATCH, 64, 0, stream>>>(emb, Aunit, norms);
  k_stats<<<1, 512, 0, stream>>>(norms, marg);
  k_main<<<98 * 32, 256, 0, stream>>>(Aunit, weight, labels, marg, partial, tlog);
  k_reduce<<<N_BATCH, 64, 0, stream>>>(partial, tlog, term);
  k_final<<<1, 512, 0, stream>>>(term, out);
}

// Round 9
// 187.798 us; speedup vs baseline: 3.2586x; 3.2586x over previous
//
#include <hip/hip_runtime.h>
#include <hip/hip_bf16.h>

#define C_NUM 100000
#define D_EMB 512
#define N_BATCH 512
#define SCALE_F 30.0f
#define MARGIN_F 0.4f
#define H_F 0.333f
#define NT2 782              // ceil(100000/128) class tiles
#define NCH 8                // 512 / 64 K-chunks

typedef __attribute__((ext_vector_type(8))) short bf16x8;
typedef __attribute__((ext_vector_type(4))) short bf16x4;
typedef __attribute__((ext_vector_type(4))) float f32x4;
typedef __attribute__((ext_vector_type(16))) float f32x16;

static __device__ __forceinline__ short f2bf(float f) {
  __hip_bfloat16 h = __float2bfloat16(f);
  union { __hip_bfloat16 b; short s; } u;
  u.b = h;
  return u.s;
}

static __device__ __forceinline__ float sq4(f32x4 v) {
  return v[0]*v[0] + v[1]*v[1] + v[2]*v[2] + v[3]*v[3];
}

// async global -> LDS: 16 B/lane; dest = wave-uniform base + lane*16
static __device__ __forceinline__ void gload16(const void* g, void* l) {
  __builtin_amdgcn_global_load_lds(
      (const __attribute__((address_space(1))) void*)g,
      (__attribute__((address_space(3))) void*)l, 16, 0, 0);
}

// ---------------------------------------------------------------------------
// Kernel 1: per-row L2 norm of embeddings; unit-normalized rows as bf16.
// ---------------------------------------------------------------------------
__global__ __launch_bounds__(64) void k_rownorm(const float* __restrict__ emb,
                                                short* __restrict__ Aunit,
                                                float* __restrict__ norms) {
  const int i = blockIdx.x;
  const int l = threadIdx.x;
  const f32x4* row = reinterpret_cast<const f32x4*>(emb + (size_t)i * D_EMB);
  f32x4 v0 = row[l];
  f32x4 v1 = row[l + 64];
  float ss = sq4(v0) + sq4(v1);
#pragma unroll
  for (int m = 1; m < 64; m <<= 1) ss += __shfl_xor(ss, m);
  float nrm = sqrtf(ss);
  float inv = 1.0f / nrm;
  bf16x4 o0, o1;
#pragma unroll
  for (int q = 0; q < 4; ++q) { o0[q] = f2bf(v0[q] * inv); o1[q] = f2bf(v1[q] * inv); }
  bf16x4* dst = reinterpret_cast<bf16x4*>(Aunit + (size_t)i * D_EMB);
  dst[l] = o0;
  dst[l + 64] = o1;
  if (l == 0) norms[i] = nrm;
}

// ---------------------------------------------------------------------------
// Kernel 2: batch mean / unbiased std -> adaptive margin per row.
// ---------------------------------------------------------------------------
__global__ __launch_bounds__(512) void k_stats(const float* __restrict__ norms,
                                               float* __restrict__ marg) {
  __shared__ float red[8];
  const int t = threadIdx.x;
  const int lane = t & 63, wid = t >> 6;
  float x = norms[t];
  float s = x;
#pragma unroll
  for (int m = 1; m < 64; m <<= 1) s += __shfl_xor(s, m);
  if (lane == 0) red[wid] = s;
  __syncthreads();
  float tot = 0.f;
#pragma unroll
  for (int q = 0; q < 8; ++q) tot += red[q];
  const float mean = tot / 512.f;
  __syncthreads();
  float d = x - mean;
  float s2 = d * d;
#pragma unroll
  for (int m = 1; m < 64; m <<= 1) s2 += __shfl_xor(s2, m);
  if (lane == 0) red[wid] = s2;
  __syncthreads();
  float tot2 = 0.f;
#pragma unroll
  for (int q = 0; q < 8; ++q) tot2 += red[q];
  const float stdv = sqrtf(tot2 / 511.f);   // ddof=1
  float msc = (x - mean) / (stdv + H_F);
  msc = fminf(1.f, fmaxf(-1.f, msc));
  marg[t] = MARGIN_F * (1.f + msc);
}

// ---------------------------------------------------------------------------
// Kernel 3: BM=128 x BN=128 x BK=64 tile GEMM, fused AdaFace epilogue.
// 512 thr = 8 waves (2 row-groups x 4 cls-groups); per wave 2 named f32x16
// accs of 32x32x16 MFMA (round-5-proven no-spill shape).
// A: bf16 via global_load_lds, linear dest + pre-swizzled global source;
// W: f32 reg-staged (ssq fused) -> cvt -> swizzled ds_write.
// Swizzle: logical (row, c) at physical row*128 + (c ^ ((row&7)<<4)).
// Double-buffered LDS, one barrier per chunk; stage issued before compute.
// ---------------------------------------------------------------------------
__global__ __launch_bounds__(512, 4) void k_main(const short* __restrict__ Aunit,
                                                 const float* __restrict__ weight,
                                                 const int* __restrict__ labels,
                                                 const float* __restrict__ marg,
                                                 float* __restrict__ partial,
                                                 float* __restrict__ tlogit) {
  __shared__ alignas(16) char As[2][16384];    // [128 rows][128 B] bf16, swizzled
  __shared__ alignas(16) char Bs2[2][16384];   // [128 cls ][128 B] bf16, swizzled
  __shared__ float winv[128];
  __shared__ float rowsum[128][4];

  const int bid = blockIdx.x;
  const int rt = bid & 3;          // row tile 0..3
  const int ct = bid >> 2;         // class tile 0..781
  const int tid = threadIdx.x;
  const int wid = tid >> 6, lane = tid & 63;

  // ---- staging roles ----
  const int scls = tid >> 2;       // class 0..127
  const int sq   = tid & 3;        // k-quarter (16 floats)
  const int xs   = (scls & 7) << 4;
  int wcl = ct * 128 + scls; if (wcl > C_NUM - 1) wcl = C_NUM - 1;
  const float* wsrc = weight + (size_t)wcl * D_EMB + sq * 16;

  // A gload sources (pre-swizzled): lane's LDS dest p = wid*2048 + i*1024 + lane*16
  const int arow_l = wid * 16 + (lane >> 3);                 // row of p0
  const int aclog  = ((lane & 7) * 16) ^ ((lane >> 3) << 4); // swizzled k-byte
  const char* gA0 = (const char*)Aunit + (size_t)(rt * 128 + arow_l) * 1024 + aclog;
  const char* gA1 = gA0 + (size_t)8 * 1024;                  // row +8 (same &7)

  // ---- compute roles ----
  const int rg = wid >> 2, cg = wid & 3;
  const int l31 = lane & 31, lhi = lane >> 5;
  const int arow = rg * 64 + l31;
  const int bcls = cg * 32 + l31;
  const int ab0 = arow * 128, ab1 = ab0 + 32 * 128;
  const int bb  = bcls * 128;
  const int xa = (arow & 7) << 4;                            // same for arow+32
  const int xb = (bcls & 7) << 4;

  f32x16 acc0, acc1;
#pragma unroll
  for (int q = 0; q < 16; ++q) { acc0[q] = 0.f; acc1[q] = 0.f; }
  float ssq = 0.f;

  // ---- prologue: stage chunk 0 ----
  {
    gload16(gA0, &As[0][wid * 2048]);
    gload16(gA1, &As[0][wid * 2048 + 1024]);
    gA0 += 128; gA1 += 128;
    f32x4 w0 = *(const f32x4*)(wsrc);
    f32x4 w1 = *(const f32x4*)(wsrc + 4);
    f32x4 w2 = *(const f32x4*)(wsrc + 8);
    f32x4 w3 = *(const f32x4*)(wsrc + 12);
    wsrc += 64;
    ssq += sq4(w0) + sq4(w1) + sq4(w2) + sq4(w3);
    bf16x8 p0, p1;
#pragma unroll
    for (int e = 0; e < 4; ++e) {
      p0[e] = f2bf(w0[e]); p0[e + 4] = f2bf(w1[e]);
      p1[e] = f2bf(w2[e]); p1[e + 4] = f2bf(w3[e]);
    }
    *(bf16x8*)(&Bs2[0][(scls * 128 + sq * 32) ^ xs]) = p0;
    *(bf16x8*)(&Bs2[0][(scls * 128 + sq * 32 + 16) ^ xs]) = p1;
  }
  __syncthreads();

  int cur = 0;
  for (int t = 0; t < NCH; ++t) {
    const bool more = t < NCH - 1;
    f32x4 w0, w1, w2, w3;
    if (more) {
      gload16(gA0, &As[cur ^ 1][wid * 2048]);
      gload16(gA1, &As[cur ^ 1][wid * 2048 + 1024]);
      gA0 += 128; gA1 += 128;
      w0 = *(const f32x4*)(wsrc);
      w1 = *(const f32x4*)(wsrc + 4);
      w2 = *(const f32x4*)(wsrc + 8);
      w3 = *(const f32x4*)(wsrc + 12);
      wsrc += 64;
    }

    // ---- compute chunk t from buf[cur] ----
    const char* Ab = As[cur];
    const char* Bb = Bs2[cur];
#pragma unroll
    for (int kk = 0; kk < 4; ++kk) {
      const int c = kk * 32 + lhi * 16;
      bf16x8 a0 = *(const bf16x8*)(Ab + ab0 + (c ^ xa));
      bf16x8 a1 = *(const bf16x8*)(Ab + ab1 + (c ^ xa));
      bf16x8 b  = *(const bf16x8*)(Bb + bb  + (c ^ xb));
      acc0 = __builtin_amdgcn_mfma_f32_32x32x16_bf16(a0, b, acc0, 0, 0, 0);
      acc1 = __builtin_amdgcn_mfma_f32_32x32x16_bf16(a1, b, acc1, 0, 0, 0);
    }

    // ---- write next W chunk (bf16) into buf[cur^1] ----
    if (more) {
      ssq += sq4(w0) + sq4(w1) + sq4(w2) + sq4(w3);
      bf16x8 p0, p1;
#pragma unroll
      for (int e = 0; e < 4; ++e) {
        p0[e] = f2bf(w0[e]); p0[e + 4] = f2bf(w1[e]);
        p1[e] = f2bf(w2[e]); p1[e + 4] = f2bf(w3[e]);
      }
      char* nb = (char*)Bs2[cur ^ 1];
      *(bf16x8*)(nb + ((scls * 128 + sq * 32) ^ xs)) = p0;
      *(bf16x8*)(nb + ((scls * 128 + sq * 32 + 16) ^ xs)) = p1;
    }
    __syncthreads();
    cur ^= 1;
  }

  // ---- per-class 1/||w||: combine the 4 k-quarter partials ----
  {
    float s = ssq;
    s += __shfl_xor(s, 1);
    s += __shfl_xor(s, 2);
    if (sq == 0) winv[scls] = (s > 0.f) ? rsqrtf(s) : 0.f;
  }
  __syncthreads();

  // ---- epilogue: margin at label, per-row exp sums ----
  // C/D layout: col = lane&31, row = (reg&3) + 8*(reg>>2) + 4*(lane>>5)
  const float wv = winv[bcls];
  const int gcc = ct * 128 + bcls;
  const bool cok = gcc < C_NUM;
#pragma unroll
  for (int mi = 0; mi < 2; ++mi) {
#pragma unroll
    for (int r = 0; r < 16; ++r) {
      const int rowf = (r & 3) + 8 * (r >> 2) + 4 * lhi;
      const int rloc = rg * 64 + mi * 32 + rowf;
      const int R = rt * 128 + rloc;
      const float cosv = (mi ? acc1[r] : acc0[r]) * wv;
      float lg = SCALE_F * cosv;
      if (labels[R] == gcc) {
        float ctv = fminf(1.f, fmaxf(-1.f, cosv));
        float lt = SCALE_F * cosf(acosf(ctv) + marg[R]);
        lg = lt;
        tlogit[R] = lt;
      }
      float v = cok ? __expf(lg) : 0.f;
      v += __shfl_xor(v, 1);
      v += __shfl_xor(v, 2);
      v += __shfl_xor(v, 4);
      v += __shfl_xor(v, 8);
      v += __shfl_xor(v, 16);
      if (l31 == 0) rowsum[rloc][cg] = v;
    }
  }
  __syncthreads();
  if (tid < 128)
    partial[(size_t)ct * N_BATCH + rt * 128 + tid] =
        (rowsum[tid][0] + rowsum[tid][1]) + (rowsum[tid][2] + rowsum[tid][3]);
}

// ---------------------------------------------------------------------------
// Kernel 4: per-row reduce over class tiles: term[r] = log(sum) - tlogit[r]
// ---------------------------------------------------------------------------
__global__ __launch_bounds__(64) void k_reduce(const float* __restrict__ partial,
                                               const float* __restrict__ tlogit,
                                               float* __restrict__ term) {
  const int r = blockIdx.x;
  const int l = threadIdx.x;
  float s = 0.f;
  for (int b = l; b < NT2; b += 64)
    s += partial[(size_t)b * N_BATCH + r];
#pragma unroll
  for (int m = 1; m < 64; m <<= 1) s += __shfl_xor(s, m);
  if (l == 0) term[r] = logf(s) - tlogit[r];
}

// ---------------------------------------------------------------------------
// Kernel 5: loss = mean(term)
// ---------------------------------------------------------------------------
__global__ __launch_bounds__(512) void k_final(const float* __restrict__ term,
                                               float* __restrict__ out) {
  __shared__ float red[8];
  const int t = threadIdx.x;
  const int lane = t & 63, wid = t >> 6;
  float v = term[t];
#pragma unroll
  for (int m = 1; m < 64; m <<= 1) v += __shfl_xor(v, m);
  if (lane == 0) red[wid] = v;
  __syncthreads();
  if (t == 0) {
    float tot = 0.f;
#pragma unroll
    for (int q = 0; q < 8; ++q) tot += red[q];
    out[0] = tot / 512.f;
  }
}

extern "C" void kernel_launch(void* const* d_in, const int* in_sizes, int n_in,
                              void* d_out, int out_size, void* d_ws, size_t ws_size,
                              hipStream_t stream) {
  const float* emb    = (const float*)d_in[0];
  const int*   labels = (const int*)d_in[1];
  const float* weight = (const float*)d_in[2];
  float* out = (float*)d_out;

  char* ws = (char*)d_ws;
  short* Aunit   = (short*)ws;                        // 512*512*2 = 524288 B
  float* norms   = (float*)(ws + 524288);             // 2 KiB
  float* marg    = (float*)(ws + 524288 + 2048);      // 2 KiB
  float* tlog    = (float*)(ws + 524288 + 4096);      // 2 KiB
  float* term    = (float*)(ws + 524288 + 6144);      // 2 KiB
  float* partial = (float*)(ws + 524288 + 8192);      // 782*512*4 = 1601536 B

  k_rownorm<<<N_BATCH, 64, 0, stream>>>(emb, Aunit, norms);
  k_stats<<<1, 512, 0, stream>>>(norms, marg);
  k_main<<<NT2 * 4, 512, 0, stream>>>(Aunit, weight, labels, marg, partial, tlog);
  k_reduce<<<N_BATCH, 64, 0, stream>>>(partial, tlog, term);
  k_final<<<1, 512, 0, stream>>>(term, out);
}

// Round 10
// 137.544 us; speedup vs baseline: 4.4491x; 1.3654x over previous
//
#include <hip/hip_runtime.h>
#include <hip/hip_bf16.h>

#define C_NUM 100000
#define D_EMB 512
#define N_BATCH 512
#define SCALE_F 30.0f
#define MARGIN_F 0.4f
#define H_F 0.333f
#define NT2 782              // ceil(100000/128) class tiles
#define NCH 16               // 512 / 32 K-chunks

typedef __attribute__((ext_vector_type(8))) short bf16x8;
typedef __attribute__((ext_vector_type(4))) short bf16x4;
typedef __attribute__((ext_vector_type(4))) float f32x4;
typedef __attribute__((ext_vector_type(16))) float f32x16;

static __device__ __forceinline__ short f2bf(float f) {
  __hip_bfloat16 h = __float2bfloat16(f);
  union { __hip_bfloat16 b; short s; } u;
  u.b = h;
  return u.s;
}

static __device__ __forceinline__ float sq4(f32x4 v) {
  return v[0]*v[0] + v[1]*v[1] + v[2]*v[2] + v[3]*v[3];
}

// async global -> LDS: 16 B/lane; dest = wave-uniform base + lane*16
static __device__ __forceinline__ void gload16(const void* g, void* l) {
  __builtin_amdgcn_global_load_lds(
      (const __attribute__((address_space(1))) void*)g,
      (__attribute__((address_space(3))) void*)l, 16, 0, 0);
}

// ---------------------------------------------------------------------------
// Kernel 1: per-row L2 norm of embeddings; unit-normalized rows as bf16.
// ---------------------------------------------------------------------------
__global__ __launch_bounds__(64) void k_rownorm(const float* __restrict__ emb,
                                                short* __restrict__ Aunit,
                                                float* __restrict__ norms) {
  const int i = blockIdx.x;
  const int l = threadIdx.x;
  const f32x4* row = reinterpret_cast<const f32x4*>(emb + (size_t)i * D_EMB);
  f32x4 v0 = row[l];
  f32x4 v1 = row[l + 64];
  float ss = sq4(v0) + sq4(v1);
#pragma unroll
  for (int m = 1; m < 64; m <<= 1) ss += __shfl_xor(ss, m);
  float nrm = sqrtf(ss);
  float inv = 1.0f / nrm;
  bf16x4 o0, o1;
#pragma unroll
  for (int q = 0; q < 4; ++q) { o0[q] = f2bf(v0[q] * inv); o1[q] = f2bf(v1[q] * inv); }
  bf16x4* dst = reinterpret_cast<bf16x4*>(Aunit + (size_t)i * D_EMB);
  dst[l] = o0;
  dst[l + 64] = o1;
  if (l == 0) norms[i] = nrm;
}

// ---------------------------------------------------------------------------
// Kernel 2: batch mean / unbiased std -> adaptive margin per row.
// ---------------------------------------------------------------------------
__global__ __launch_bounds__(512) void k_stats(const float* __restrict__ norms,
                                               float* __restrict__ marg) {
  __shared__ float red[8];
  const int t = threadIdx.x;
  const int lane = t & 63, wid = t >> 6;
  float x = norms[t];
  float s = x;
#pragma unroll
  for (int m = 1; m < 64; m <<= 1) s += __shfl_xor(s, m);
  if (lane == 0) red[wid] = s;
  __syncthreads();
  float tot = 0.f;
#pragma unroll
  for (int q = 0; q < 8; ++q) tot += red[q];
  const float mean = tot / 512.f;
  __syncthreads();
  float d = x - mean;
  float s2 = d * d;
#pragma unroll
  for (int m = 1; m < 64; m <<= 1) s2 += __shfl_xor(s2, m);
  if (lane == 0) red[wid] = s2;
  __syncthreads();
  float tot2 = 0.f;
#pragma unroll
  for (int q = 0; q < 8; ++q) tot2 += red[q];
  const float stdv = sqrtf(tot2 / 511.f);   // ddof=1
  float msc = (x - mean) / (stdv + H_F);
  msc = fminf(1.f, fmaxf(-1.f, msc));
  marg[t] = MARGIN_F * (1.f + msc);
}

// ---------------------------------------------------------------------------
// Kernel 3: BM=128 x BN=128 x BK=32, 256 thr = 4 waves (32 rows x 128 cls
// each, 4 named f32x16 accs). 4 independent blocks/CU -> barrier stalls of
// one block hide under the others' MFMA.
// A: bf16 gload_lds, [128][64B] with both-sides XOR ((row>>1)&3)<<4.
// W: f32 reg-staged -> bf16, LDS rows padded to 80 B (5*cls mod 8 walks all
//    granules -> conflict-free reads), double-buffered.
// Grid 98x32: the 4 rt-sharers of each ct are 8 bids apart -> same XCD.
// ---------------------------------------------------------------------------
__global__ __launch_bounds__(256, 4) void k_main(const short* __restrict__ Aunit,
                                                 const float* __restrict__ weight,
                                                 const int* __restrict__ labels,
                                                 const float* __restrict__ marg,
                                                 float* __restrict__ partial,
                                                 float* __restrict__ tlogit) {
  __shared__ alignas(16) char As[2][8192];     // [128 rows][64 B] bf16, swizzled
  __shared__ alignas(16) char Ws[2][10240];    // [128 cls][80 B] bf16, padded
  __shared__ float winv[128];

  const int bid = blockIdx.x;
  const int grp = bid >> 5, within = bid & 31;
  const int rt = (within >> 3) & 3;            // 0..3
  const int ct = grp * 8 + (within & 7);
  if (ct >= NT2) return;

  const int tid = threadIdx.x;                 // 0..255
  const int w = tid >> 6, lane = tid & 63;
  const int l31 = lane & 31, lhi = lane >> 5;

  // ---- A gload source (pre-swizzled): dest p = w*2048 + i*1024 + lane*16 ----
  const int ar0 = w * 32 + (lane >> 2);                  // row of i=0 segment
  const int ak0 = ((lane & 3) * 16) ^ (((ar0 >> 1) & 3) << 4);
  const char* gA0 = (const char*)Aunit + (size_t)(rt * 128 + ar0) * 1024 + ak0;
  const char* gA1 = gA0 + (size_t)16 * 1024;             // row+16: same swizzle

  // ---- W stage roles: round r covers cls r*32+sc8, unit su (16 B of f32) ----
  const int sc8 = tid >> 3;        // 0..31
  const int su  = tid & 7;         // 0..7
  const float* wsrc[4];
  int wdst[4];
#pragma unroll
  for (int r = 0; r < 4; ++r) {
    int cls = r * 32 + sc8;
    int gcl = ct * 128 + cls; if (gcl > C_NUM - 1) gcl = C_NUM - 1;
    wsrc[r] = weight + (size_t)gcl * D_EMB + su * 4;
    wdst[r] = cls * 80 + su * 8;
  }

  // ---- compute-side LDS offsets ----
  const int xa = ((l31 >> 1) & 3) << 4;        // A swizzle (row = w*32+l31)
  const int abase = (w * 32 + l31) * 64;

  f32x16 acc0, acc1, acc2, acc3;
#pragma unroll
  for (int q = 0; q < 16; ++q) { acc0[q] = 0.f; acc1[q] = 0.f; acc2[q] = 0.f; acc3[q] = 0.f; }
  float ssq0 = 0.f, ssq1 = 0.f, ssq2 = 0.f, ssq3 = 0.f;

  // ---- prologue: stage chunk 0 into buffer 0 ----
  {
    gload16(gA0, &As[0][w * 2048]);
    gload16(gA1, &As[0][w * 2048 + 1024]);
    gA0 += 64; gA1 += 64;
    f32x4 v0 = *(const f32x4*)(wsrc[0]); wsrc[0] += 32;
    f32x4 v1 = *(const f32x4*)(wsrc[1]); wsrc[1] += 32;
    f32x4 v2 = *(const f32x4*)(wsrc[2]); wsrc[2] += 32;
    f32x4 v3 = *(const f32x4*)(wsrc[3]); wsrc[3] += 32;
    ssq0 += sq4(v0); ssq1 += sq4(v1); ssq2 += sq4(v2); ssq3 += sq4(v3);
    bf16x4 p0, p1, p2, p3;
#pragma unroll
    for (int e = 0; e < 4; ++e) { p0[e] = f2bf(v0[e]); p1[e] = f2bf(v1[e]);
                                  p2[e] = f2bf(v2[e]); p3[e] = f2bf(v3[e]); }
    *(bf16x4*)(&Ws[0][wdst[0]]) = p0;
    *(bf16x4*)(&Ws[0][wdst[1]]) = p1;
    *(bf16x4*)(&Ws[0][wdst[2]]) = p2;
    *(bf16x4*)(&Ws[0][wdst[3]]) = p3;
  }
  __syncthreads();

  int cur = 0;
  for (int c = 0; c < NCH; ++c) {
    const bool more = c < NCH - 1;
    f32x4 v0, v1, v2, v3;
    if (more) {
      gload16(gA0, &As[cur ^ 1][w * 2048]);
      gload16(gA1, &As[cur ^ 1][w * 2048 + 1024]);
      gA0 += 64; gA1 += 64;
      v0 = *(const f32x4*)(wsrc[0]); wsrc[0] += 32;
      v1 = *(const f32x4*)(wsrc[1]); wsrc[1] += 32;
      v2 = *(const f32x4*)(wsrc[2]); wsrc[2] += 32;
      v3 = *(const f32x4*)(wsrc[3]); wsrc[3] += 32;
    }

    // ---- compute chunk c from buf[cur] ----
    const char* Ab = As[cur];
    const char* Wb = Ws[cur];
#pragma unroll
    for (int kk = 0; kk < 2; ++kk) {
      const int kb = kk * 32 + lhi * 16;
      bf16x8 a  = *(const bf16x8*)(Ab + abase + (kb ^ xa));
      bf16x8 b0 = *(const bf16x8*)(Wb + (l31)       * 80 + kb);
      bf16x8 b1 = *(const bf16x8*)(Wb + (32  + l31) * 80 + kb);
      bf16x8 b2 = *(const bf16x8*)(Wb + (64  + l31) * 80 + kb);
      bf16x8 b3 = *(const bf16x8*)(Wb + (96  + l31) * 80 + kb);
      acc0 = __builtin_amdgcn_mfma_f32_32x32x16_bf16(a, b0, acc0, 0, 0, 0);
      acc1 = __builtin_amdgcn_mfma_f32_32x32x16_bf16(a, b1, acc1, 0, 0, 0);
      acc2 = __builtin_amdgcn_mfma_f32_32x32x16_bf16(a, b2, acc2, 0, 0, 0);
      acc3 = __builtin_amdgcn_mfma_f32_32x32x16_bf16(a, b3, acc3, 0, 0, 0);
    }

    // ---- write next W chunk into buf[cur^1] ----
    if (more) {
      ssq0 += sq4(v0); ssq1 += sq4(v1); ssq2 += sq4(v2); ssq3 += sq4(v3);
      bf16x4 p0, p1, p2, p3;
#pragma unroll
      for (int e = 0; e < 4; ++e) { p0[e] = f2bf(v0[e]); p1[e] = f2bf(v1[e]);
                                    p2[e] = f2bf(v2[e]); p3[e] = f2bf(v3[e]); }
      char* nb = (char*)Ws[cur ^ 1];
      *(bf16x4*)(nb + wdst[0]) = p0;
      *(bf16x4*)(nb + wdst[1]) = p1;
      *(bf16x4*)(nb + wdst[2]) = p2;
      *(bf16x4*)(nb + wdst[3]) = p3;
    }
    __syncthreads();
    cur ^= 1;
  }

  // ---- per-class 1/||w||: reduce over the 8 su units ----
  {
    float s0 = ssq0, s1 = ssq1, s2 = ssq2, s3 = ssq3;
#pragma unroll
    for (int m = 1; m < 8; m <<= 1) {
      s0 += __shfl_xor(s0, m); s1 += __shfl_xor(s1, m);
      s2 += __shfl_xor(s2, m); s3 += __shfl_xor(s3, m);
    }
    if (su == 0) {
      winv[sc8]      = (s0 > 0.f) ? rsqrtf(s0) : 0.f;
      winv[32 + sc8] = (s1 > 0.f) ? rsqrtf(s1) : 0.f;
      winv[64 + sc8] = (s2 > 0.f) ? rsqrtf(s2) : 0.f;
      winv[96 + sc8] = (s3 > 0.f) ? rsqrtf(s3) : 0.f;
    }
  }
  __syncthreads();

  // ---- epilogue: margin at label, per-row exp sums (wave-complete rows) ----
  // C/D layout: col = lane&31, row = (reg&3) + 8*(reg>>2) + 4*(lane>>5)
  const float wv0 = winv[l31];
  const float wv1 = winv[32 + l31];
  const float wv2 = winv[64 + l31];
  const float wv3 = winv[96 + l31];
  const int cb = ct * 128;
#pragma unroll
  for (int r = 0; r < 16; ++r) {
    const int rowf = (r & 3) + 8 * (r >> 2) + 4 * lhi;
    const int R = rt * 128 + w * 32 + rowf;
    const int lab = labels[R];
    float v = 0.f;
#pragma unroll
    for (int ni = 0; ni < 4; ++ni) {
      const int gcc = cb + ni * 32 + l31;
      const float wv = (ni == 0) ? wv0 : (ni == 1) ? wv1 : (ni == 2) ? wv2 : wv3;
      const float av = (ni == 0) ? acc0[r] : (ni == 1) ? acc1[r] : (ni == 2) ? acc2[r] : acc3[r];
      const float cosv = av * wv;
      float lg = SCALE_F * cosv;
      if (lab == gcc) {
        float ctv = fminf(1.f, fmaxf(-1.f, cosv));
        float lt = SCALE_F * cosf(acosf(ctv) + marg[R]);
        lg = lt;
        tlogit[R] = lt;
      }
      v += (gcc < C_NUM) ? __expf(lg) : 0.f;
    }
    v += __shfl_xor(v, 1);
    v += __shfl_xor(v, 2);
    v += __shfl_xor(v, 4);
    v += __shfl_xor(v, 8);
    v += __shfl_xor(v, 16);
    if (l31 == 0) partial[(size_t)ct * N_BATCH + R] = v;
  }
}

// ---------------------------------------------------------------------------
// Kernel 4: per-row reduce over class tiles: term[r] = log(sum) - tlogit[r]
// ---------------------------------------------------------------------------
__global__ __launch_bounds__(64) void k_reduce(const float* __restrict__ partial,
                                               const float* __restrict__ tlogit,
                                               float* __restrict__ term) {
  const int r = blockIdx.x;
  const int l = threadIdx.x;
  float s = 0.f;
  for (int b = l; b < NT2; b += 64)
    s += partial[(size_t)b * N_BATCH + r];
#pragma unroll
  for (int m = 1; m < 64; m <<= 1) s += __shfl_xor(s, m);
  if (l == 0) term[r] = logf(s) - tlogit[r];
}

// ---------------------------------------------------------------------------
// Kernel 5: loss = mean(term)
// ---------------------------------------------------------------------------
__global__ __launch_bounds__(512) void k_final(const float* __restrict__ term,
                                               float* __restrict__ out) {
  __shared__ float red[8];
  const int t = threadIdx.x;
  const int lane = t & 63, wid = t >> 6;
  float v = term[t];
#pragma unroll
  for (int m = 1; m < 64; m <<= 1) v += __shfl_xor(v, m);
  if (lane == 0) red[wid] = v;
  __syncthreads();
  if (t == 0) {
    float tot = 0.f;
#pragma unroll
    for (int q = 0; q < 8; ++q) tot += red[q];
    out[0] = tot / 512.f;
  }
}

extern "C" void kernel_launch(void* const* d_in, const int* in_sizes, int n_in,
                              void* d_out, int out_size, void* d_ws, size_t ws_size,
                              hipStream_t stream) {
  const float* emb    = (const float*)d_in[0];
  const int*   labels = (const int*)d_in[1];
  const float* weight = (const float*)d_in[2];
  float* out = (float*)d_out;

  char* ws = (char*)d_ws;
  short* Aunit   = (short*)ws;                        // 512*512*2 = 524288 B
  float* norms   = (float*)(ws + 524288);             // 2 KiB
  float* marg    = (float*)(ws + 524288 + 2048);      // 2 KiB
  float* tlog    = (float*)(ws + 524288 + 4096);      // 2 KiB
  float* term    = (float*)(ws + 524288 + 6144);      // 2 KiB
  float* partial = (float*)(ws + 524288 + 8192);      // 782*512*4 = 1601536 B

  k_rownorm<<<N_BATCH, 64, 0, stream>>>(emb, Aunit, norms);
  k_stats<<<1, 512, 0, stream>>>(norms, marg);
  k_main<<<98 * 32, 256, 0, stream>>>(Aunit, weight, labels, marg, partial, tlog);
  k_reduce<<<N_BATCH, 64, 0, stream>>>(partial, tlog, term);
  k_final<<<1, 512, 0, stream>>>(term, out);
}

// Round 11
// 134.627 us; speedup vs baseline: 4.5455x; 1.0217x over previous
//
#include <hip/hip_runtime.h>
#include <hip/hip_bf16.h>

#define C_NUM 100000
#define D_EMB 512
#define N_BATCH 512
#define SCALE_F 30.0f
#define MARGIN_F 0.4f
#define H_F 0.333f
#define NT2 782              // ceil(100000/128) class tiles
#define NCH 16               // 512 / 32 K-chunks

typedef __attribute__((ext_vector_type(8))) short bf16x8;
typedef __attribute__((ext_vector_type(4))) short bf16x4;
typedef __attribute__((ext_vector_type(4))) float f32x4;
typedef __attribute__((ext_vector_type(16))) float f32x16;

static __device__ __forceinline__ short f2bf(float f) {
  __hip_bfloat16 h = __float2bfloat16(f);
  union { __hip_bfloat16 b; short s; } u;
  u.b = h;
  return u.s;
}

static __device__ __forceinline__ float sq4(f32x4 v) {
  return v[0]*v[0] + v[1]*v[1] + v[2]*v[2] + v[3]*v[3];
}

// async global -> LDS: 16 B/lane; dest = wave-uniform base + lane*16
static __device__ __forceinline__ void gload16(const void* g, void* l) {
  __builtin_amdgcn_global_load_lds(
      (const __attribute__((address_space(1))) void*)g,
      (__attribute__((address_space(3))) void*)l, 16, 0, 0);
}

// ---------------------------------------------------------------------------
// Kernel 1: per-row L2 norm of embeddings; unit-normalized rows as bf16.
// ---------------------------------------------------------------------------
__global__ __launch_bounds__(64) void k_rownorm(const float* __restrict__ emb,
                                                short* __restrict__ Aunit,
                                                float* __restrict__ norms) {
  const int i = blockIdx.x;
  const int l = threadIdx.x;
  const f32x4* row = reinterpret_cast<const f32x4*>(emb + (size_t)i * D_EMB);
  f32x4 v0 = row[l];
  f32x4 v1 = row[l + 64];
  float ss = sq4(v0) + sq4(v1);
#pragma unroll
  for (int m = 1; m < 64; m <<= 1) ss += __shfl_xor(ss, m);
  float nrm = sqrtf(ss);
  float inv = 1.0f / nrm;
  bf16x4 o0, o1;
#pragma unroll
  for (int q = 0; q < 4; ++q) { o0[q] = f2bf(v0[q] * inv); o1[q] = f2bf(v1[q] * inv); }
  bf16x4* dst = reinterpret_cast<bf16x4*>(Aunit + (size_t)i * D_EMB);
  dst[l] = o0;
  dst[l + 64] = o1;
  if (l == 0) norms[i] = nrm;
}

// ---------------------------------------------------------------------------
// Kernel 2: batch mean / unbiased std -> adaptive margin per row.
// ---------------------------------------------------------------------------
__global__ __launch_bounds__(512) void k_stats(const float* __restrict__ norms,
                                               float* __restrict__ marg) {
  __shared__ float red[8];
  const int t = threadIdx.x;
  const int lane = t & 63, wid = t >> 6;
  float x = norms[t];
  float s = x;
#pragma unroll
  for (int m = 1; m < 64; m <<= 1) s += __shfl_xor(s, m);
  if (lane == 0) red[wid] = s;
  __syncthreads();
  float tot = 0.f;
#pragma unroll
  for (int q = 0; q < 8; ++q) tot += red[q];
  const float mean = tot / 512.f;
  __syncthreads();
  float d = x - mean;
  float s2 = d * d;
#pragma unroll
  for (int m = 1; m < 64; m <<= 1) s2 += __shfl_xor(s2, m);
  if (lane == 0) red[wid] = s2;
  __syncthreads();
  float tot2 = 0.f;
#pragma unroll
  for (int q = 0; q < 8; ++q) tot2 += red[q];
  const float stdv = sqrtf(tot2 / 511.f);   // ddof=1
  float msc = (x - mean) / (stdv + H_F);
  msc = fminf(1.f, fmaxf(-1.f, msc));
  marg[t] = MARGIN_F * (1.f + msc);
}

// ---------------------------------------------------------------------------
// Kernel 3: R10 frame + counted-vmcnt pipeline (T4) + setprio (T5).
// Per phase: issue A(c+1) gloads, issue W(c+2) reg-loads, compute chunk c,
// s_waitcnt vmcnt(4) (A+W(c+1) drained, W(c+2) stays IN FLIGHT across the
// barrier), ds_write W(c+1), lgkmcnt(0), s_barrier. W loads lead their use
// by ~2 chunk-times -> HBM latency hidden.
// ---------------------------------------------------------------------------
__global__ __launch_bounds__(256, 3) void k_main(const short* __restrict__ Aunit,
                                                 const float* __restrict__ weight,
                                                 const int* __restrict__ labels,
                                                 const float* __restrict__ marg,
                                                 float* __restrict__ partial,
                                                 float* __restrict__ tlogit) {
  __shared__ alignas(16) char As[2][8192];     // [128 rows][64 B] bf16, swizzled
  __shared__ alignas(16) char Ws[2][10240];    // [128 cls][80 B] bf16, padded
  __shared__ float winv[128];

  const int bid = blockIdx.x;
  const int grp = bid >> 5, within = bid & 31;
  const int rt = (within >> 3) & 3;            // 0..3
  const int ct = grp * 8 + (within & 7);
  if (ct >= NT2) return;

  const int tid = threadIdx.x;                 // 0..255
  const int w = tid >> 6, lane = tid & 63;
  const int l31 = lane & 31, lhi = lane >> 5;

  // ---- A gload source (pre-swizzled): dest p = w*2048 + i*1024 + lane*16 ----
  const int ar0 = w * 32 + (lane >> 2);
  const int ak0 = ((lane & 3) * 16) ^ (((ar0 >> 1) & 3) << 4);
  const char* gAb0 = (const char*)Aunit + (size_t)(rt * 128 + ar0) * 1024 + ak0;
  const char* gAb1 = gAb0 + (size_t)16 * 1024;

  // ---- W stage roles ----
  const int sc8 = tid >> 3;        // 0..31
  const int su  = tid & 7;         // 0..7
  const float* wbase0; const float* wbase1; const float* wbase2; const float* wbase3;
  int wdst0, wdst1, wdst2, wdst3;
  {
    int c0 = 0 * 32 + sc8, c1 = 1 * 32 + sc8, c2 = 2 * 32 + sc8, c3 = 3 * 32 + sc8;
    int g0 = ct * 128 + c0; if (g0 > C_NUM - 1) g0 = C_NUM - 1;
    int g1 = ct * 128 + c1; if (g1 > C_NUM - 1) g1 = C_NUM - 1;
    int g2 = ct * 128 + c2; if (g2 > C_NUM - 1) g2 = C_NUM - 1;
    int g3 = ct * 128 + c3; if (g3 > C_NUM - 1) g3 = C_NUM - 1;
    wbase0 = weight + (size_t)g0 * D_EMB + su * 4;
    wbase1 = weight + (size_t)g1 * D_EMB + su * 4;
    wbase2 = weight + (size_t)g2 * D_EMB + su * 4;
    wbase3 = weight + (size_t)g3 * D_EMB + su * 4;
    wdst0 = c0 * 80 + su * 8; wdst1 = c1 * 80 + su * 8;
    wdst2 = c2 * 80 + su * 8; wdst3 = c3 * 80 + su * 8;
  }

  // ---- compute-side LDS offsets ----
  const int xa = ((l31 >> 1) & 3) << 4;
  const int abase = (w * 32 + l31) * 64;

  f32x16 acc0, acc1, acc2, acc3;
#pragma unroll
  for (int q = 0; q < 16; ++q) { acc0[q] = 0.f; acc1[q] = 0.f; acc2[q] = 0.f; acc3[q] = 0.f; }
  float ssq0 = 0.f, ssq1 = 0.f, ssq2 = 0.f, ssq3 = 0.f;

  f32x4 pa0, pa1, pa2, pa3;   // one W-chunk reg set
  f32x4 pb0, pb1, pb2, pb3;   // the other

#define WLOAD(R0,R1,R2,R3,OFF) { \
    R0 = *(const f32x4*)(wbase0 + (OFF)); R1 = *(const f32x4*)(wbase1 + (OFF)); \
    R2 = *(const f32x4*)(wbase2 + (OFF)); R3 = *(const f32x4*)(wbase3 + (OFF)); }

#define WWRITE(BUF,R0,R1,R2,R3) { \
    bf16x4 t0, t1, t2, t3; \
    _Pragma("unroll") \
    for (int e = 0; e < 4; ++e) { t0[e] = f2bf(R0[e]); t1[e] = f2bf(R1[e]); \
                                  t2[e] = f2bf(R2[e]); t3[e] = f2bf(R3[e]); } \
    *(bf16x4*)(&Ws[BUF][wdst0]) = t0; *(bf16x4*)(&Ws[BUF][wdst1]) = t1; \
    *(bf16x4*)(&Ws[BUF][wdst2]) = t2; *(bf16x4*)(&Ws[BUF][wdst3]) = t3; }

#define SSQADD(R0,R1,R2,R3) { ssq0 += sq4(R0); ssq1 += sq4(R1); \
                              ssq2 += sq4(R2); ssq3 += sq4(R3); }

#define COMPUTE(BUF) { \
    const char* Ab = As[BUF]; const char* Wb = Ws[BUF]; \
    __builtin_amdgcn_s_setprio(1); \
    _Pragma("unroll") \
    for (int kk = 0; kk < 2; ++kk) { \
      const int kb = kk * 32 + lhi * 16; \
      bf16x8 a  = *(const bf16x8*)(Ab + abase + (kb ^ xa)); \
      bf16x8 b0 = *(const bf16x8*)(Wb + (l31)      * 80 + kb); \
      bf16x8 b1 = *(const bf16x8*)(Wb + (32 + l31) * 80 + kb); \
      bf16x8 b2 = *(const bf16x8*)(Wb + (64 + l31) * 80 + kb); \
      bf16x8 b3 = *(const bf16x8*)(Wb + (96 + l31) * 80 + kb); \
      acc0 = __builtin_amdgcn_mfma_f32_32x32x16_bf16(a, b0, acc0, 0, 0, 0); \
      acc1 = __builtin_amdgcn_mfma_f32_32x32x16_bf16(a, b1, acc1, 0, 0, 0); \
      acc2 = __builtin_amdgcn_mfma_f32_32x32x16_bf16(a, b2, acc2, 0, 0, 0); \
      acc3 = __builtin_amdgcn_mfma_f32_32x32x16_bf16(a, b3, acc3, 0, 0, 0); \
    } \
    __builtin_amdgcn_s_setprio(0); }

  // ---- prologue: pa <- W(0); A(0) -> As[0]; pb <- W(1) ----
  WLOAD(pa0, pa1, pa2, pa3, 0);
  __builtin_amdgcn_sched_barrier(0);
  gload16(gAb0, &As[0][w * 2048]);
  gload16(gAb1, &As[0][w * 2048 + 1024]);
  __builtin_amdgcn_sched_barrier(0);
  WLOAD(pb0, pb1, pb2, pb3, 32);
  __builtin_amdgcn_sched_barrier(0);
  asm volatile("s_waitcnt vmcnt(4)" ::: "memory");   // pa + A(0) done; pb flying
  SSQADD(pa0, pa1, pa2, pa3);
  WWRITE(0, pa0, pa1, pa2, pa3);
  asm volatile("s_waitcnt lgkmcnt(0)" ::: "memory");
  __builtin_amdgcn_s_barrier();
  __builtin_amdgcn_sched_barrier(0);

  for (int i = 0; i < 8; ++i) {
    // ===== even chunk c = 2i: reads As[0]/Ws[0]; pb holds W(2i+1) =====
    {
      const int ao = (2 * i + 1) * 64;                 // A(2i+1), never clamps
      gload16(gAb0 + ao, &As[1][w * 2048]);
      gload16(gAb1 + ao, &As[1][w * 2048 + 1024]);
      __builtin_amdgcn_sched_barrier(0);
      int cw = 2 * i + 2; if (cw > 15) cw = 15;        // W(2i+2) -> pa
      WLOAD(pa0, pa1, pa2, pa3, cw * 32);
      __builtin_amdgcn_sched_barrier(0);
      COMPUTE(0);
      asm volatile("s_waitcnt vmcnt(4)" ::: "memory"); // pb + A(2i+1) done; pa flying
      SSQADD(pb0, pb1, pb2, pb3);                      // W(2i+1), always valid
      WWRITE(1, pb0, pb1, pb2, pb3);
      asm volatile("s_waitcnt lgkmcnt(0)" ::: "memory");
      __builtin_amdgcn_s_barrier();
      __builtin_amdgcn_sched_barrier(0);
    }
    // ===== odd chunk c = 2i+1: reads As[1]/Ws[1]; pa holds W(2i+2) =====
    {
      int ca = 2 * i + 2; if (ca > 15) ca = 15;        // A(2i+2) -> As[0]
      const int ao = ca * 64;
      gload16(gAb0 + ao, &As[0][w * 2048]);
      gload16(gAb1 + ao, &As[0][w * 2048 + 1024]);
      __builtin_amdgcn_sched_barrier(0);
      int cw = 2 * i + 3; if (cw > 15) cw = 15;        // W(2i+3) -> pb
      WLOAD(pb0, pb1, pb2, pb3, cw * 32);
      __builtin_amdgcn_sched_barrier(0);
      COMPUTE(1);
      asm volatile("s_waitcnt vmcnt(4)" ::: "memory"); // pa + A done; pb flying
      if (2 * i + 2 <= 15) SSQADD(pa0, pa1, pa2, pa3); // guard double-count at tail
      WWRITE(0, pa0, pa1, pa2, pa3);
      asm volatile("s_waitcnt lgkmcnt(0)" ::: "memory");
      __builtin_amdgcn_s_barrier();
      __builtin_amdgcn_sched_barrier(0);
    }
  }

  // ---- per-class 1/||w||: reduce over the 8 su units ----
  {
    float s0 = ssq0, s1 = ssq1, s2 = ssq2, s3 = ssq3;
#pragma unroll
    for (int m = 1; m < 8; m <<= 1) {
      s0 += __shfl_xor(s0, m); s1 += __shfl_xor(s1, m);
      s2 += __shfl_xor(s2, m); s3 += __shfl_xor(s3, m);
    }
    if (su == 0) {
      winv[sc8]      = (s0 > 0.f) ? rsqrtf(s0) : 0.f;
      winv[32 + sc8] = (s1 > 0.f) ? rsqrtf(s1) : 0.f;
      winv[64 + sc8] = (s2 > 0.f) ? rsqrtf(s2) : 0.f;
      winv[96 + sc8] = (s3 > 0.f) ? rsqrtf(s3) : 0.f;
    }
  }
  __syncthreads();

  // ---- epilogue: margin at label, per-row exp sums ----
  // C/D layout: col = lane&31, row = (reg&3) + 8*(reg>>2) + 4*(lane>>5)
  const float wv0 = winv[l31];
  const float wv1 = winv[32 + l31];
  const float wv2 = winv[64 + l31];
  const float wv3 = winv[96 + l31];
  const int cb = ct * 128;
#pragma unroll
  for (int r = 0; r < 16; ++r) {
    const int rowf = (r & 3) + 8 * (r >> 2) + 4 * lhi;
    const int R = rt * 128 + w * 32 + rowf;
    const int lab = labels[R];
    float v = 0.f;
#pragma unroll
    for (int ni = 0; ni < 4; ++ni) {
      const int gcc = cb + ni * 32 + l31;
      const float wv = (ni == 0) ? wv0 : (ni == 1) ? wv1 : (ni == 2) ? wv2 : wv3;
      const float av = (ni == 0) ? acc0[r] : (ni == 1) ? acc1[r] : (ni == 2) ? acc2[r] : acc3[r];
      const float cosv = av * wv;
      float lg = SCALE_F * cosv;
      if (lab == gcc) {
        float ctv = fminf(1.f, fmaxf(-1.f, cosv));
        float lt = SCALE_F * cosf(acosf(ctv) + marg[R]);
        lg = lt;
        tlogit[R] = lt;
      }
      v += (gcc < C_NUM) ? __expf(lg) : 0.f;
    }
    v += __shfl_xor(v, 1);
    v += __shfl_xor(v, 2);
    v += __shfl_xor(v, 4);
    v += __shfl_xor(v, 8);
    v += __shfl_xor(v, 16);
    if (l31 == 0) partial[(size_t)ct * N_BATCH + R] = v;
  }
#undef WLOAD
#undef WWRITE
#undef SSQADD
#undef COMPUTE
}

// ---------------------------------------------------------------------------
// Kernel 4: per-row reduce over class tiles: term[r] = log(sum) - tlogit[r]
// ---------------------------------------------------------------------------
__global__ __launch_bounds__(64) void k_reduce(const float* __restrict__ partial,
                                               const float* __restrict__ tlogit,
                                               float* __restrict__ term) {
  const int r = blockIdx.x;
  const int l = threadIdx.x;
  float s = 0.f;
  for (int b = l; b < NT2; b += 64)
    s += partial[(size_t)b * N_BATCH + r];
#pragma unroll
  for (int m = 1; m < 64; m <<= 1) s += __shfl_xor(s, m);
  if (l == 0) term[r] = logf(s) - tlogit[r];
}

// ---------------------------------------------------------------------------
// Kernel 5: loss = mean(term)
// ---------------------------------------------------------------------------
__global__ __launch_bounds__(512) void k_final(const float* __restrict__ term,
                                               float* __restrict__ out) {
  __shared__ float red[8];
  const int t = threadIdx.x;
  const int lane = t & 63, wid = t >> 6;
  float v = term[t];
#pragma unroll
  for (int m = 1; m < 64; m <<= 1) v += __shfl_xor(v, m);
  if (lane == 0) red[wid] = v;
  __syncthreads();
  if (t == 0) {
    float tot = 0.f;
#pragma unroll
    for (int q = 0; q < 8; ++q) tot += red[q];
    out[0] = tot / 512.f;
  }
}

extern "C" void kernel_launch(void* const* d_in, const int* in_sizes, int n_in,
                              void* d_out, int out_size, void* d_ws, size_t ws_size,
                              hipStream_t stream) {
  const float* emb    = (const float*)d_in[0];
  const int*   labels = (const int*)d_in[1];
  const float* weight = (const float*)d_in[2];
  float* out = (float*)d_out;

  char* ws = (char*)d_ws;
  short* Aunit   = (short*)ws;                        // 512*512*2 = 524288 B
  float* norms   = (float*)(ws + 524288);             // 2 KiB
  float* marg    = (float*)(ws + 524288 + 2048);      // 2 KiB
  float* tlog    = (float*)(ws + 524288 + 4096);      // 2 KiB
  float* term    = (float*)(ws + 524288 + 6144);      // 2 KiB
  float* partial = (float*)(ws + 524288 + 8192);      // 782*512*4 = 1601536 B

  k_rownorm<<<N_BATCH, 64, 0, stream>>>(emb, Aunit, norms);
  k_stats<<<1, 512, 0, stream>>>(norms, marg);
  k_main<<<98 * 32, 256, 0, stream>>>(Aunit, weight, labels, marg, partial, tlog);
  k_reduce<<<N_BATCH, 64, 0, stream>>>(partial, tlog, term);
  k_final<<<1, 512, 0, stream>>>(term, out);
}